// Round 9
// baseline (464.073 us; speedup 1.0000x reference)
//
#include <hip/hip_runtime.h>
#include <hip/hip_cooperative_groups.h>
#include <stdint.h>

namespace cg = cooperative_groups;

#define NN 50000
#define NB 196              // ceil(NN/256)
#define NTILES 782          // ceil(NN/64) gemm tiles
#define NCHUNK 3125         // NN/16 agg chunks
#define NEG_SLOPE 0.2f
#define WTS 136             // padded W^T row stride (u16)

// output layout (element offsets)
#define IXZ_OFF    (NN * 64)
#define SKL_OFF    (NN * 64 + NN)
#define MEAN_OFF   (NN * 64 + NN + 1)
#define STD_OFF    (MEAN_OFF + NN * 64)

typedef unsigned int u32;
typedef unsigned short u16;
typedef __attribute__((ext_vector_type(8))) short short8;
typedef __attribute__((ext_vector_type(4))) float f32x4;

__device__ __forceinline__ float bf2f(u16 s) { return __uint_as_float(((u32)s) << 16); }
__device__ __forceinline__ u16 f2bf(float f) {
    u32 u = __float_as_uint(f);
    u += 0x7FFFu + ((u >> 16) & 1u);   // RNE
    return (u16)(u >> 16);
}
__device__ __forceinline__ float lo16(u32 u) { return __uint_as_float(u << 16); }
__device__ __forceinline__ float hi16(u32 u) { return __uint_as_float(u & 0xFFFF0000u); }
__device__ __forceinline__ float softplusf(float x) {
    return fmaxf(x, 0.f) + log1pf(expf(-fabsf(x)));
}
__device__ __forceinline__ void stout(void* o, long long idx, float v, bool f32) {
    if (f32) ((float*)o)[idx] = v;
    else     ((u16*)o)[idx]   = f2bf(v);
}
__device__ __forceinline__ int wscan_incl(int v, int lane) {
#pragma unroll
    for (int off = 1; off < 64; off <<= 1) {
        int u = __shfl_up(v, off);
        if (lane >= off) v += u;
    }
    return v;
}

// dtype detect: bf16 data -> low u16 of dwords has sane bf16 exponent
__device__ __forceinline__ bool detect_f32_block(const u32* __restrict__ xw,
                                                 int* lflag)
{
    const int t = threadIdx.x;
    if (t < 64) {
        u32 wrd = xw[t];
        u32 e = (wrd >> 7) & 0xFF;
        bool plaus = (e >= 0x60 && e <= 0x85);
        unsigned long long b = __ballot(plaus);
        if (t == 0) *lflag = (__popcll(b) < 32) ? 1 : 0;
    }
    __syncthreads();
    return *lflag != 0;
}

// W (k,c) -> padded global W^T image (bf16); kb in [0,8)
__device__ __forceinline__ void wt_body(const void* __restrict__ wv_,
                                        u16* __restrict__ wtg,
                                        int kb, int tid, bool f32)
{
    const int k = kb * 16 + (tid >> 4);
    const int cq = tid & 15;
    u16 v[8];
    if (f32) {
        const float* w = (const float*)wv_;
        float4 a = *(const float4*)(w + k * 128 + cq * 8);
        float4 b = *(const float4*)(w + k * 128 + cq * 8 + 4);
        v[0] = f2bf(a.x); v[1] = f2bf(a.y); v[2] = f2bf(a.z); v[3] = f2bf(a.w);
        v[4] = f2bf(b.x); v[5] = f2bf(b.y); v[6] = f2bf(b.z); v[7] = f2bf(b.w);
    } else {
        const u16* w = (const u16*)wv_;
        uint4 u = *(const uint4*)(w + k * 128 + cq * 8);
        v[0] = (u16)(u.x & 0xFFFF); v[1] = (u16)(u.x >> 16);
        v[2] = (u16)(u.y & 0xFFFF); v[3] = (u16)(u.y >> 16);
        v[4] = (u16)(u.z & 0xFFFF); v[5] = (u16)(u.z >> 16);
        v[6] = (u16)(u.w & 0xFFFF); v[7] = (u16)(u.w >> 16);
    }
#pragma unroll
    for (int j = 0; j < 8; j++)
        wtg[(cq * 8 + j) * WTS + k] = v[j];
}

// MFMA GEMM for one 64-node tile. ls = 128*WTS u16 LDS.
__device__ __forceinline__ void gemm_tile(
    const void* __restrict__ xv, const u16* __restrict__ wtg,
    const void* __restrict__ attv, bool f32,
    u16* __restrict__ hb, float* __restrict__ ai, float* __restrict__ aj,
    int tile, int tid, u16* ls)
{
    __syncthreads();   // prior users of ls done
    {
        uint4* d = (uint4*)ls;
        const uint4* s = (const uint4*)wtg;
        for (int i = tid; i < 128 * WTS / 8; i += 256) d[i] = s[i];
    }

    const int w = tid >> 6, L = tid & 63;
    const int q = L >> 4, c15 = L & 15;
    const int nb16 = tile * 64 + w * 16;

    short8 afr[4];
    {
        int nrow = nb16 + c15; if (nrow > NN - 1) nrow = NN - 1;
        if (f32) {
            const float* xp = (const float*)xv + (size_t)nrow * 128 + q * 8;
#pragma unroll
            for (int ks = 0; ks < 4; ks++) {
                float4 a = *(const float4*)(xp + ks * 32);
                float4 b = *(const float4*)(xp + ks * 32 + 4);
                union { short8 s; u16 e[8]; } u;
                u.e[0] = f2bf(a.x); u.e[1] = f2bf(a.y); u.e[2] = f2bf(a.z); u.e[3] = f2bf(a.w);
                u.e[4] = f2bf(b.x); u.e[5] = f2bf(b.y); u.e[6] = f2bf(b.z); u.e[7] = f2bf(b.w);
                afr[ks] = u.s;
            }
        } else {
            const u16* xp = (const u16*)xv + (size_t)nrow * 128 + q * 8;
#pragma unroll
            for (int ks = 0; ks < 4; ks++)
                afr[ks] = *(const short8*)(xp + ks * 32);
        }
    }
    __syncthreads();

    f32x4 acc[8];
#pragma unroll
    for (int t = 0; t < 8; t++) {
        acc[t] = (f32x4){0.f, 0.f, 0.f, 0.f};
        const u16* bp = ls + (16 * t + c15) * WTS + q * 8;
#pragma unroll
        for (int ks = 0; ks < 4; ks++) {
            short8 bfr = *(const short8*)(bp + ks * 32);
            acc[t] = __builtin_amdgcn_mfma_f32_16x16x32_bf16(afr[ks], bfr, acc[t], 0, 0, 0);
        }
    }

    float ati[8], atj[8];
#pragma unroll
    for (int t = 0; t < 8; t++) {
        int p = (t >> 1) * 64 + (t & 1) * 16 + c15;
        if (f32) {
            ati[t] = ((const float*)attv)[p];
            atj[t] = ((const float*)attv)[p + 32];
        } else {
            ati[t] = bf2f(((const u16*)attv)[p]);
            atj[t] = bf2f(((const u16*)attv)[p + 32]);
        }
    }
#pragma unroll
    for (int r = 0; r < 4; r++) {
        int node = nb16 + q * 4 + r;
#pragma unroll
        for (int h = 0; h < 4; h++) {
            float pi = acc[2 * h][r] * ati[2 * h] + acc[2 * h + 1][r] * ati[2 * h + 1];
            float pj = acc[2 * h][r] * atj[2 * h] + acc[2 * h + 1][r] * atj[2 * h + 1];
            pi += __shfl_xor(pi, 1); pj += __shfl_xor(pj, 1);
            pi += __shfl_xor(pi, 2); pj += __shfl_xor(pj, 2);
            pi += __shfl_xor(pi, 4); pj += __shfl_xor(pj, 4);
            pi += __shfl_xor(pi, 8); pj += __shfl_xor(pj, 8);
            if (c15 == 0 && node < NN) { ai[node * 4 + h] = pi; aj[node * 4 + h] = pj; }
        }
    }

    __syncthreads();   // all waves done reading W^T before overwrite
    u16* myls = ls + w * 16 * WTS;
#pragma unroll
    for (int t = 0; t < 8; t++)
#pragma unroll
        for (int r = 0; r < 4; r++)
            myls[(q * 4 + r) * WTS + 16 * t + c15] = f2bf(acc[t][r]);
#pragma unroll
    for (int v = 0; v < 4; v++) {
        int idx = v * 64 + L;
        int nrow = idx >> 4, c8 = idx & 15;
        int node = nb16 + nrow;
        if (node < NN)
            *(uint4*)(hb + (size_t)node * 128 + c8 * 8) =
                *(const uint4*)(myls + nrow * WTS + c8 * 8);
    }
}

// per-256-chunk exclusive prefix (lexcl) + chunk sums; sb in [0,NB)
__device__ __forceinline__ void scan1_body(const int* __restrict__ counts,
                                           int* __restrict__ lexcl,
                                           int* __restrict__ blocksum,
                                           int sb, int* wsum)
{
    const int t = threadIdx.x, lane = t & 63, wv = t >> 6;
    const int i = sb * 256 + t;
    int c = (i < NN) ? counts[i] : 0;
    int inc = wscan_incl(c, lane);
    if (lane == 63) wsum[wv] = inc;
    __syncthreads();
    int add = 0;
#pragma unroll
    for (int k = 0; k < 3; k++) if (k < wv) add += wsum[k];
    inc += add;
    if (i < NN) lexcl[i] = inc - c;
    if (t == 255) blocksum[sb] = inc;
}

// exclusive scan of NB blocksums into sboff[256]
__device__ __forceinline__ void sboff_body(const int* __restrict__ blocksum,
                                           int* sboff, int* wsum)
{
    const int t = threadIdx.x, lane = t & 63, wv = t >> 6;
    int c = (t < NB) ? blocksum[t] : 0;
    int inc = wscan_incl(c, lane);
    if (lane == 63) wsum[wv] = inc;
    __syncthreads();
    int add = 0;
#pragma unroll
    for (int k = 0; k < 3; k++) if (k < wv) add += wsum[k];
    sboff[t] = inc + add - c;
    __syncthreads();
}

// CSR fill for one edge
__device__ __forceinline__ void fill_edge(const int* __restrict__ src,
                                          const int* __restrict__ dst,
                                          const int* __restrict__ lexcl,
                                          const int* sboff,
                                          int* __restrict__ cursor,
                                          int* __restrict__ perm_src, int e)
{
    int d = dst[e];
    int pos = sboff[d >> 8] + lexcl[d] + atomicAdd(&cursor[d], 1);
    perm_src[pos] = src[e];
}

// aggregation+finalize for 16 nodes (256 threads, 16 lanes/node)
__device__ __forceinline__ void agg_chunk(
    const int* __restrict__ lexcl, const int* sboff,
    const int* __restrict__ counts, const int* __restrict__ perm_src,
    const float* __restrict__ ai, const float* __restrict__ aj,
    const u16* __restrict__ hb, const void* __restrict__ biasv,
    bool f32, void* __restrict__ outv, int chunk)
{
    const int tid = threadIdx.x;
    const int node = chunk * 16 + (tid >> 4);
    const int l = tid & 15;
    const int head = l >> 2;
    const int cc0 = (l & 3) << 3;

    const int rs = sboff[node >> 8] + lexcl[node];
    const int re = rs + counts[node];
    const float ain = ai[node * 4 + head];
    const u16* hl8 = hb + l * 8;

    float dsum = 0.f;
    float a0 = 0.f, a1 = 0.f, a2 = 0.f, a3 = 0.f;
    float a4 = 0.f, a5 = 0.f, a6 = 0.f, a7 = 0.f;

    int i = rs;
    for (; i + 1 < re; i += 2) {
        int s0 = perm_src[i], s1 = perm_src[i + 1];
        float x0 = aj[s0 * 4 + head] + ain;
        float x1 = aj[s1 * 4 + head] + ain;
        x0 = x0 > 0.f ? x0 : NEG_SLOPE * x0;
        x1 = x1 > 0.f ? x1 : NEG_SLOPE * x1;
        float e0 = __expf(x0), e1 = __expf(x1);
        uint4 h0 = *(const uint4*)(hl8 + (size_t)s0 * 128);
        uint4 h1 = *(const uint4*)(hl8 + (size_t)s1 * 128);
        dsum += e0 + e1;
        a0 += e0 * lo16(h0.x) + e1 * lo16(h1.x);
        a1 += e0 * hi16(h0.x) + e1 * hi16(h1.x);
        a2 += e0 * lo16(h0.y) + e1 * lo16(h1.y);
        a3 += e0 * hi16(h0.y) + e1 * hi16(h1.y);
        a4 += e0 * lo16(h0.z) + e1 * lo16(h1.z);
        a5 += e0 * hi16(h0.z) + e1 * hi16(h1.z);
        a6 += e0 * lo16(h0.w) + e1 * lo16(h1.w);
        a7 += e0 * hi16(h0.w) + e1 * hi16(h1.w);
    }
    if (i < re) {
        int s0 = perm_src[i];
        float x0 = aj[s0 * 4 + head] + ain;
        x0 = x0 > 0.f ? x0 : NEG_SLOPE * x0;
        float e0 = __expf(x0);
        uint4 h0 = *(const uint4*)(hl8 + (size_t)s0 * 128);
        dsum += e0;
        a0 += e0 * lo16(h0.x); a1 += e0 * hi16(h0.x);
        a2 += e0 * lo16(h0.y); a3 += e0 * hi16(h0.y);
        a4 += e0 * lo16(h0.z); a5 += e0 * hi16(h0.z);
        a6 += e0 * lo16(h0.w); a7 += e0 * hi16(h0.w);
    }

    const float inv = 1.f / (dsum + 1e-16f);
    const int cb = head * 32 + cc0;
    float v[8];
    if (f32) {
        const float* bias = (const float*)biasv;
#pragma unroll
        for (int j = 0; j < 8; j++) v[j] = bias[cb + j];
    } else {
        const u16* bias = (const u16*)biasv;
#pragma unroll
        for (int j = 0; j < 8; j++) v[j] = bf2f(bias[cb + j]);
    }
    v[0] += a0 * inv; v[1] += a1 * inv; v[2] += a2 * inv; v[3] += a3 * inv;
    v[4] += a4 * inv; v[5] += a5 * inv; v[6] += a6 * inv; v[7] += a7 * inv;

    float part = 0.f;
    if (cc0 < 16) {
#pragma unroll
        for (int j = 0; j < 8; j++) part += 0.5f * v[j] * v[j];
        long long o = (long long)node * 64 + head * 16 + cc0;
#pragma unroll
        for (int j = 0; j < 8; j++) stout(outv, o + j, v[j], f32);
        long long om = (long long)MEAN_OFF + o;
#pragma unroll
        for (int j = 0; j < 8; j++) stout(outv, om + j, v[j], f32);
    } else {
        long long os = (long long)STD_OFF + (long long)node * 64 + head * 16 + (cc0 - 16);
#pragma unroll
        for (int j = 0; j < 8; j++) {
            float s = softplusf(v[j] - 5.f) + 1e-10f;
            part += -logf(s) + 0.5f * s * s - 0.5f;
            stout(outv, os + j, s, f32);
        }
    }
    part += __shfl_xor(part, 1); part += __shfl_xor(part, 2);
    part += __shfl_xor(part, 4); part += __shfl_xor(part, 8);
    if (l == 0) stout(outv, (long long)IXZ_OFF + node, part * 0.25f, f32);
}

// ---------------------------------------------------------------------------
// Cooperative mega-kernel: the whole pipeline in one dispatch.
// ---------------------------------------------------------------------------
__global__ __launch_bounds__(256, 4) void k_all(
    const void* __restrict__ xv, const int* __restrict__ ei,
    const void* __restrict__ wv, const void* __restrict__ attv,
    const void* __restrict__ biasv, void* __restrict__ outv,
    u16* __restrict__ hb, float* __restrict__ ai, float* __restrict__ aj,
    int* __restrict__ perm_src, int* __restrict__ counts,
    int* __restrict__ cursor, int* __restrict__ lexcl,
    int* __restrict__ blocksum, u16* __restrict__ wtg, int E)
{
    __shared__ __align__(16) u16 ls[128 * WTS];
    __shared__ int sboff[256];
    __shared__ int wsum[4];
    __shared__ int lflag;

    cg::grid_group gg = cg::this_grid();
    const int tid = threadIdx.x, bid = blockIdx.x, gdim = gridDim.x;
    const int* src = ei;
    const int* dst = ei + E;

    const bool f32 = detect_f32_block((const u32*)xv, &lflag);

    // P0: zero counts+cursor (contiguous); blocks 0..7 build W^T image
    for (int i = bid * 256 + tid; i < 2 * NN; i += gdim * 256) counts[i] = 0;
    if (bid < 8) wt_body(wv, wtg, bid, tid, f32);
    gg.sync();

    // P1: GEMM tiles + degree count
    for (int tile = bid; tile < NTILES; tile += gdim)
        gemm_tile(xv, wtg, attv, f32, hb, ai, aj, tile, tid, ls);
    for (int e = bid * 256 + tid; e < E; e += gdim * 256)
        atomicAdd(&counts[dst[e]], 1);
    gg.sync();

    // P2: scan1
    for (int sb = bid; sb < NB; sb += gdim) {
        scan1_body(counts, lexcl, blocksum, sb, wsum);
        __syncthreads();
    }
    gg.sync();

    // P3: fill (sboff scan once per block)
    sboff_body(blocksum, sboff, wsum);
    for (int e = bid * 256 + tid; e < E; e += gdim * 256)
        fill_edge(src, dst, lexcl, sboff, cursor, perm_src, e);
    gg.sync();

    // P4: aggregation + finalize (sboff persists in LDS)
    for (int c = bid; c < NCHUNK; c += gdim)
        agg_chunk(lexcl, sboff, counts, perm_src, ai, aj, hb, biasv, f32, outv, c);
    if (bid == 0 && tid == 0) stout(outv, (long long)SKL_OFF, 0.f, f32);
}

// ---------------------------------------------------------------------------
// Fallback kernels (classic 5-dispatch path), used only if cooperative
// launch is unavailable.
// ---------------------------------------------------------------------------
__global__ __launch_bounds__(256) void k_wt(const void* __restrict__ xv,
                                            const void* __restrict__ wv,
                                            u16* __restrict__ wtg,
                                            int* __restrict__ zbase)
{
    __shared__ int lflag;
    const bool f32 = detect_f32_block((const u32*)xv, &lflag);
    const int t = threadIdx.x;
    for (int i = blockIdx.x * 256 + t; i < 2 * NN; i += 8 * 256) zbase[i] = 0;
    wt_body(wv, wtg, blockIdx.x, t, f32);
}

__global__ __launch_bounds__(256) void k_gemm(
    const void* __restrict__ xv, const u16* __restrict__ wtg,
    const void* __restrict__ attv, u16* __restrict__ hb,
    float* __restrict__ ai, float* __restrict__ aj,
    const int* __restrict__ dst, int* __restrict__ counts, int E)
{
    __shared__ __align__(16) u16 ls[128 * WTS];
    __shared__ int lflag;
    const bool f32 = detect_f32_block((const u32*)xv, &lflag);
    gemm_tile(xv, wtg, attv, f32, hb, ai, aj, blockIdx.x, threadIdx.x, ls);
    for (int e = blockIdx.x * 256 + threadIdx.x; e < E; e += gridDim.x * 256)
        atomicAdd(&counts[dst[e]], 1);
}

__global__ __launch_bounds__(256) void k_scan1(const int* __restrict__ counts,
                                               int* __restrict__ lexcl,
                                               int* __restrict__ blocksum)
{
    __shared__ int wsum[4];
    scan1_body(counts, lexcl, blocksum, blockIdx.x, wsum);
}

__global__ __launch_bounds__(256) void k_fill(
    const int* __restrict__ ei, const int* __restrict__ lexcl,
    const int* __restrict__ blocksum, int* __restrict__ cursor,
    int* __restrict__ perm_src, int E)
{
    __shared__ int sboff[256];
    __shared__ int wsum[4];
    sboff_body(blocksum, sboff, wsum);
    int e = blockIdx.x * 256 + threadIdx.x;
    if (e < E) fill_edge(ei, ei + E, lexcl, sboff, cursor, perm_src, e);
}

__global__ __launch_bounds__(256) void k_agg(
    const int* __restrict__ lexcl, const int* __restrict__ blocksum,
    const int* __restrict__ counts, const int* __restrict__ perm_src,
    const float* __restrict__ ai, const float* __restrict__ aj,
    const u16* __restrict__ hb, const void* __restrict__ biasv,
    const void* __restrict__ xv, void* __restrict__ outv)
{
    __shared__ int sboff[256];
    __shared__ int wsum[4];
    __shared__ int lflag;
    const bool f32 = detect_f32_block((const u32*)xv, &lflag);
    sboff_body(blocksum, sboff, wsum);
    agg_chunk(lexcl, sboff, counts, perm_src, ai, aj, hb, biasv, f32, outv,
              blockIdx.x);
    if (blockIdx.x == 0 && threadIdx.x == 0)
        stout(outv, (long long)SKL_OFF, 0.f, f32);
}

// ---------------------------------------------------------------------------
extern "C" void kernel_launch(void* const* d_in, const int* in_sizes, int n_in,
                              void* d_out, int out_size, void* d_ws, size_t ws_size,
                              hipStream_t stream)
{
    const void* x    = d_in[0];
    const int*  ei   = (const int*)d_in[1];
    const void* w    = d_in[2];
    const void* att  = d_in[3];
    const void* bias = d_in[4];
    int E = in_sizes[1] / 2;

    // workspace (~17.8 MB): hb | ai | aj | perm_src | counts | cursor |
    //                       lexcl | blocksum | wtg
    u16*   hb       = (u16*)d_ws;                      // NN*128 bf16
    float* ai       = (float*)(hb + (size_t)NN * 128);
    float* aj       = ai + NN * 4;
    int*   perm_src = (int*)(aj + NN * 4);             // E
    int*   counts   = perm_src + E;                    // NN
    int*   cursor   = counts + NN;                     // NN (contiguous!)
    int*   lexcl    = cursor + NN;                     // NN
    int*   blocksum = lexcl + NN;                      // NB
    u16*   wtg      = (u16*)(((uintptr_t)(blocksum + NB) + 15) & ~(uintptr_t)15);

    int maxB = 0;
    hipError_t qerr = hipOccupancyMaxActiveBlocksPerMultiprocessor(
        &maxB, (const void*)k_all, 256, 0);
    int nb = (qerr == hipSuccess && maxB > 0) ? maxB * 256 : 512;
    if (nb > 1024) nb = 1024;
    if (nb < 256)  nb = 256;

    void* outp = d_out;
    void* args[] = {(void*)&x, (void*)&ei, (void*)&w, (void*)&att, (void*)&bias,
                    (void*)&outp, (void*)&hb, (void*)&ai, (void*)&aj,
                    (void*)&perm_src, (void*)&counts, (void*)&cursor,
                    (void*)&lexcl, (void*)&blocksum, (void*)&wtg, (void*)&E};
    hipError_t lerr = hipLaunchCooperativeKernel(
        (const void*)k_all, dim3(nb), dim3(256), args, 0, stream);

    if (lerr != hipSuccess) {
        // fallback: classic 5-dispatch pipeline
        k_wt<<<8, 256, 0, stream>>>(x, w, wtg, counts);
        k_gemm<<<NTILES, 256, 0, stream>>>(x, wtg, att, hb, ai, aj,
                                           ei + E, counts, E);
        k_scan1<<<NB, 256, 0, stream>>>(counts, lexcl, blocksum);
        k_fill<<<(E + 255) / 256, 256, 0, stream>>>(ei, lexcl, blocksum,
                                                    cursor, perm_src, E);
        k_agg<<<NCHUNK, 256, 0, stream>>>(lexcl, blocksum, counts, perm_src,
                                          ai, aj, hb, bias, x, d_out);
    }
}

// Round 10
// 208.189 us; speedup vs baseline: 2.2291x; 2.2291x over previous
//
#include <hip/hip_runtime.h>
#include <stdint.h>

#define NN 50000
#define NB 196              // ceil(NN/256)
#define NTILES 782          // ceil(NN/64) gemm tiles
#define NEG_SLOPE 0.2f
#define WTS 136             // padded W^T row stride (u16)

// output layout (element offsets)
#define IXZ_OFF    (NN * 64)
#define SKL_OFF    (NN * 64 + NN)
#define MEAN_OFF   (NN * 64 + NN + 1)
#define STD_OFF    (MEAN_OFF + NN * 64)

typedef unsigned int u32;
typedef unsigned short u16;
typedef unsigned char u8;
typedef __attribute__((ext_vector_type(8))) short short8;
typedef __attribute__((ext_vector_type(4))) float f32x4;
typedef __attribute__((ext_vector_type(2))) float f32x2;

__device__ __forceinline__ float bf2f(u16 s) { return __uint_as_float(((u32)s) << 16); }
__device__ __forceinline__ u16 f2bf(float f) {
    u32 u = __float_as_uint(f);
    u += 0x7FFFu + ((u >> 16) & 1u);   // RNE
    return (u16)(u >> 16);
}
__device__ __forceinline__ float lo16(u32 u) { return __uint_as_float(u << 16); }
__device__ __forceinline__ float hi16(u32 u) { return __uint_as_float(u & 0xFFFF0000u); }
__device__ __forceinline__ float softplusf(float x) {
    return fmaxf(x, 0.f) + log1pf(expf(-fabsf(x)));
}
__device__ __forceinline__ void stout(void* o, long long idx, float v, bool f32) {
    if (f32) ((float*)o)[idx] = v;
    else     ((u16*)o)[idx]   = f2bf(v);
}
__device__ __forceinline__ int wscan_incl(int v, int lane) {
#pragma unroll
    for (int off = 1; off < 64; off <<= 1) {
        int u = __shfl_up(v, off);
        if (lane >= off) v += u;
    }
    return v;
}

// dtype detect: bf16 data -> low u16 of dwords has sane bf16 exponent
__device__ __forceinline__ bool detect_f32_block(const u32* __restrict__ xw,
                                                 int* lflag)
{
    const int t = threadIdx.x;
    if (t < 64) {
        u32 wrd = xw[t];
        u32 e = (wrd >> 7) & 0xFF;
        bool plaus = (e >= 0x60 && e <= 0x85);
        unsigned long long b = __ballot(plaus);
        if (t == 0) *lflag = (__popcll(b) < 32) ? 1 : 0;
    }
    __syncthreads();
    return *lflag != 0;
}

// ---------------------------------------------------------------------------
// k_wt: 64 blocks. Zero counts+cursor+done; blocks 0..7 transpose W into the
// padded global W^T image (bf16).
// ---------------------------------------------------------------------------
__global__ __launch_bounds__(256) void k_wt(const void* __restrict__ xv,
                                            const void* __restrict__ wv_,
                                            u16* __restrict__ wtg,
                                            int* __restrict__ zbase)
{
    __shared__ int lflag;
    const bool f32 = detect_f32_block((const u32*)xv, &lflag);
    const int t = threadIdx.x;

    for (int i = blockIdx.x * 256 + t; i < 2 * NN + 1; i += 64 * 256)
        zbase[i] = 0;

    if (blockIdx.x < 8) {
        const int k = blockIdx.x * 16 + (t >> 4);
        const int cq = t & 15;
        u16 v[8];
        if (f32) {
            const float* w = (const float*)wv_;
            float4 a = *(const float4*)(w + k * 128 + cq * 8);
            float4 b = *(const float4*)(w + k * 128 + cq * 8 + 4);
            v[0] = f2bf(a.x); v[1] = f2bf(a.y); v[2] = f2bf(a.z); v[3] = f2bf(a.w);
            v[4] = f2bf(b.x); v[5] = f2bf(b.y); v[6] = f2bf(b.z); v[7] = f2bf(b.w);
        } else {
            const u16* w = (const u16*)wv_;
            uint4 u = *(const uint4*)(w + k * 128 + cq * 8);
            v[0] = (u16)(u.x & 0xFFFF); v[1] = (u16)(u.x >> 16);
            v[2] = (u16)(u.y & 0xFFFF); v[3] = (u16)(u.y >> 16);
            v[4] = (u16)(u.z & 0xFFFF); v[5] = (u16)(u.z >> 16);
            v[6] = (u16)(u.w & 0xFFFF); v[7] = (u16)(u.w >> 16);
        }
#pragma unroll
        for (int j = 0; j < 8; j++)
            wtg[(cq * 8 + j) * WTS + k] = v[j];
    }
}

// ---------------------------------------------------------------------------
// MFMA GEMM: h = x @ W -> fp8 e4m3 hb. Wave = 16 nodes x 128 ch.
// Tail: grid-stride dst-degree count.
// ---------------------------------------------------------------------------
__global__ __launch_bounds__(256) void k_gemm(
    const void* __restrict__ xv, const u16* __restrict__ wtg,
    const void* __restrict__ attv, u8* __restrict__ hb,
    float* __restrict__ ai, float* __restrict__ aj,
    const int* __restrict__ dst, int* __restrict__ counts, int E)
{
    __shared__ __align__(16) u16 ls[128 * WTS];   // 34816 B
    __shared__ int lflag;
    const bool f32 = detect_f32_block((const u32*)xv, &lflag);
    const int tid = threadIdx.x;

    {
        uint4* d = (uint4*)ls;
        const uint4* s = (const uint4*)wtg;
        for (int i = tid; i < 128 * WTS / 8; i += 256) d[i] = s[i];
    }

    const int w = tid >> 6, L = tid & 63;
    const int q = L >> 4, c15 = L & 15;
    const int nb16 = blockIdx.x * 64 + w * 16;

    short8 afr[4];
    {
        int nrow = nb16 + c15; if (nrow > NN - 1) nrow = NN - 1;
        if (f32) {
            const float* xp = (const float*)xv + (size_t)nrow * 128 + q * 8;
#pragma unroll
            for (int ks = 0; ks < 4; ks++) {
                float4 a = *(const float4*)(xp + ks * 32);
                float4 b = *(const float4*)(xp + ks * 32 + 4);
                union { short8 s; u16 e[8]; } u;
                u.e[0] = f2bf(a.x); u.e[1] = f2bf(a.y); u.e[2] = f2bf(a.z); u.e[3] = f2bf(a.w);
                u.e[4] = f2bf(b.x); u.e[5] = f2bf(b.y); u.e[6] = f2bf(b.z); u.e[7] = f2bf(b.w);
                afr[ks] = u.s;
            }
        } else {
            const u16* xp = (const u16*)xv + (size_t)nrow * 128 + q * 8;
#pragma unroll
            for (int ks = 0; ks < 4; ks++)
                afr[ks] = *(const short8*)(xp + ks * 32);
        }
    }
    __syncthreads();

    f32x4 acc[8];
#pragma unroll
    for (int t = 0; t < 8; t++) {
        acc[t] = (f32x4){0.f, 0.f, 0.f, 0.f};
        const u16* bp = ls + (16 * t + c15) * WTS + q * 8;
#pragma unroll
        for (int ks = 0; ks < 4; ks++) {
            short8 bfr = *(const short8*)(bp + ks * 32);
            acc[t] = __builtin_amdgcn_mfma_f32_16x16x32_bf16(afr[ks], bfr, acc[t], 0, 0, 0);
        }
    }

    float ati[8], atj[8];
#pragma unroll
    for (int t = 0; t < 8; t++) {
        int p = (t >> 1) * 64 + (t & 1) * 16 + c15;
        if (f32) {
            ati[t] = ((const float*)attv)[p];
            atj[t] = ((const float*)attv)[p + 32];
        } else {
            ati[t] = bf2f(((const u16*)attv)[p]);
            atj[t] = bf2f(((const u16*)attv)[p + 32]);
        }
    }
#pragma unroll
    for (int r = 0; r < 4; r++) {
        int node = nb16 + q * 4 + r;
#pragma unroll
        for (int h = 0; h < 4; h++) {
            float pi = acc[2 * h][r] * ati[2 * h] + acc[2 * h + 1][r] * ati[2 * h + 1];
            float pj = acc[2 * h][r] * atj[2 * h] + acc[2 * h + 1][r] * atj[2 * h + 1];
            pi += __shfl_xor(pi, 1); pj += __shfl_xor(pj, 1);
            pi += __shfl_xor(pi, 2); pj += __shfl_xor(pj, 2);
            pi += __shfl_xor(pi, 4); pj += __shfl_xor(pj, 4);
            pi += __shfl_xor(pi, 8); pj += __shfl_xor(pj, 8);
            if (c15 == 0 && node < NN) { ai[node * 4 + h] = pi; aj[node * 4 + h] = pj; }
        }
    }

    __syncthreads();   // all waves done reading W^T before overwrite
    u16* myls = ls + w * 16 * WTS;
#pragma unroll
    for (int t = 0; t < 8; t++)
#pragma unroll
        for (int r = 0; r < 4; r++)
            myls[(q * 4 + r) * WTS + 16 * t + c15] = f2bf(acc[t][r]);
    // read back 8 bf16, convert to 8 fp8 e4m3, store 8B coalesced
#pragma unroll
    for (int v = 0; v < 4; v++) {
        int idx = v * 64 + L;
        int nrow = idx >> 4, c8 = idx & 15;
        int node = nb16 + nrow;
        uint4 t16 = *(const uint4*)(myls + nrow * WTS + c8 * 8);
        float f0 = lo16(t16.x), f1 = hi16(t16.x);
        float f2 = lo16(t16.y), f3 = hi16(t16.y);
        float f4 = lo16(t16.z), f5 = hi16(t16.z);
        float f6 = lo16(t16.w), f7 = hi16(t16.w);
        u32 lo = 0, hi = 0;
        lo = __builtin_amdgcn_cvt_pk_fp8_f32(f0, f1, lo, false);
        lo = __builtin_amdgcn_cvt_pk_fp8_f32(f2, f3, lo, true);
        hi = __builtin_amdgcn_cvt_pk_fp8_f32(f4, f5, hi, false);
        hi = __builtin_amdgcn_cvt_pk_fp8_f32(f6, f7, hi, true);
        if (node < NN) {
            uint2 o; o.x = lo; o.y = hi;
            *(uint2*)(hb + (size_t)node * 128 + c8 * 8) = o;
        }
    }

    const int gid = blockIdx.x * 256 + tid;
    const int stride = gridDim.x * 256;
    for (int e = gid; e < E; e += stride)
        atomicAdd(&counts[dst[e]], 1);
}

// ---------------------------------------------------------------------------
// k_scan1: local prefix + blocksum; LAST block scans the NB blocksums into
// global sboff_g (fence + done-counter pattern).
// ---------------------------------------------------------------------------
__global__ __launch_bounds__(256) void k_scan1(const int* __restrict__ counts,
                                               int* __restrict__ lexcl,
                                               int* __restrict__ blocksum,
                                               int* __restrict__ done,
                                               int* __restrict__ sboff_g)
{
    __shared__ int wsum[4];
    __shared__ int sboff[256];
    __shared__ int lastf;
    const int t = threadIdx.x, lane = t & 63, wv = t >> 6;
    const int i = blockIdx.x * 256 + t;
    int c = (i < NN) ? counts[i] : 0;
    int inc = wscan_incl(c, lane);
    if (lane == 63) wsum[wv] = inc;
    __syncthreads();
    int add = 0;
#pragma unroll
    for (int k = 0; k < 3; k++) if (k < wv) add += wsum[k];
    inc += add;
    if (i < NN) lexcl[i] = inc - c;
    if (t == 255) {
        blocksum[blockIdx.x] = inc;
        __threadfence();
        lastf = (atomicAdd(done, 1) == NB - 1) ? 1 : 0;
    }
    __syncthreads();
    if (lastf) {
        __threadfence();
        int c2 = (t < NB) ? blocksum[t] : 0;
        int inc2 = wscan_incl(c2, lane);
        if (lane == 63) wsum[wv] = inc2;
        __syncthreads();
        int add2 = 0;
#pragma unroll
        for (int k = 0; k < 3; k++) if (k < wv) add2 += wsum[k];
        sboff[t] = inc2 + add2 - c2;
        __syncthreads();
        sboff_g[t] = sboff[t];
    }
}

// ---------------------------------------------------------------------------
// k_fill: CSR scatter using global sboff_g
// ---------------------------------------------------------------------------
__global__ __launch_bounds__(256) void k_fill(
    const int* __restrict__ ei, const int* __restrict__ lexcl,
    const int* __restrict__ sboff_g, int* __restrict__ cursor,
    int* __restrict__ perm_src, int E)
{
    int e = blockIdx.x * 256 + threadIdx.x;
    if (e >= E) return;
    int d = ei[E + e];                    // dst
    int pos = sboff_g[d >> 8] + lexcl[d] + atomicAdd(&cursor[d], 1);
    perm_src[pos] = ei[e];                // src
}

// ---------------------------------------------------------------------------
// Aggregation + finalize: 16 threads/node, lane l -> channels 8l..8l+7,
// head = l>>2. fp8 hb gathers via v_cvt_pk_f32_fp8; single-pass softmax.
// ---------------------------------------------------------------------------
__global__ __launch_bounds__(256) void k_agg(
    const int* __restrict__ lexcl, const int* __restrict__ sboff_g,
    const int* __restrict__ counts, const int* __restrict__ perm_src,
    const float* __restrict__ ai, const float* __restrict__ aj,
    const u8* __restrict__ hb, const void* __restrict__ biasv,
    const void* __restrict__ xv, void* __restrict__ outv)
{
    __shared__ int lflag;
    const bool f32 = detect_f32_block((const u32*)xv, &lflag);
    const int t = blockIdx.x * 256 + threadIdx.x;
    const int node = t >> 4;
    const int l = t & 15;
    const int head = l >> 2;
    const int cc0 = (l & 3) << 3;

    const int rs = sboff_g[node >> 8] + lexcl[node];
    const int re = rs + counts[node];
    const float ain = ai[node * 4 + head];
    const u8* hl8 = hb + l * 8;

    float dsum = 0.f;
    float a0 = 0.f, a1 = 0.f, a2 = 0.f, a3 = 0.f;
    float a4 = 0.f, a5 = 0.f, a6 = 0.f, a7 = 0.f;

    int i = rs;
    for (; i + 1 < re; i += 2) {
        int s0 = perm_src[i], s1 = perm_src[i + 1];
        float x0 = aj[s0 * 4 + head] + ain;
        float x1 = aj[s1 * 4 + head] + ain;
        x0 = x0 > 0.f ? x0 : NEG_SLOPE * x0;
        x1 = x1 > 0.f ? x1 : NEG_SLOPE * x1;
        float e0 = __expf(x0), e1 = __expf(x1);
        uint2 h0 = *(const uint2*)(hl8 + (size_t)s0 * 128);
        uint2 h1 = *(const uint2*)(hl8 + (size_t)s1 * 128);
        f32x2 p0 = __builtin_amdgcn_cvt_pk_f32_fp8(h0.x, false);
        f32x2 p1 = __builtin_amdgcn_cvt_pk_f32_fp8(h0.x, true);
        f32x2 p2 = __builtin_amdgcn_cvt_pk_f32_fp8(h0.y, false);
        f32x2 p3 = __builtin_amdgcn_cvt_pk_f32_fp8(h0.y, true);
        f32x2 q0 = __builtin_amdgcn_cvt_pk_f32_fp8(h1.x, false);
        f32x2 q1 = __builtin_amdgcn_cvt_pk_f32_fp8(h1.x, true);
        f32x2 q2 = __builtin_amdgcn_cvt_pk_f32_fp8(h1.y, false);
        f32x2 q3 = __builtin_amdgcn_cvt_pk_f32_fp8(h1.y, true);
        dsum += e0 + e1;
        a0 += e0 * p0.x + e1 * q0.x;  a1 += e0 * p0.y + e1 * q0.y;
        a2 += e0 * p1.x + e1 * q1.x;  a3 += e0 * p1.y + e1 * q1.y;
        a4 += e0 * p2.x + e1 * q2.x;  a5 += e0 * p2.y + e1 * q2.y;
        a6 += e0 * p3.x + e1 * q3.x;  a7 += e0 * p3.y + e1 * q3.y;
    }
    if (i < re) {
        int s0 = perm_src[i];
        float x0 = aj[s0 * 4 + head] + ain;
        x0 = x0 > 0.f ? x0 : NEG_SLOPE * x0;
        float e0 = __expf(x0);
        uint2 h0 = *(const uint2*)(hl8 + (size_t)s0 * 128);
        f32x2 p0 = __builtin_amdgcn_cvt_pk_f32_fp8(h0.x, false);
        f32x2 p1 = __builtin_amdgcn_cvt_pk_f32_fp8(h0.x, true);
        f32x2 p2 = __builtin_amdgcn_cvt_pk_f32_fp8(h0.y, false);
        f32x2 p3 = __builtin_amdgcn_cvt_pk_f32_fp8(h0.y, true);
        dsum += e0;
        a0 += e0 * p0.x; a1 += e0 * p0.y;
        a2 += e0 * p1.x; a3 += e0 * p1.y;
        a4 += e0 * p2.x; a5 += e0 * p2.y;
        a6 += e0 * p3.x; a7 += e0 * p3.y;
    }

    const float inv = 1.f / (dsum + 1e-16f);
    const int cb = head * 32 + cc0;
    float v[8];
    if (f32) {
        const float* bias = (const float*)biasv;
#pragma unroll
        for (int j = 0; j < 8; j++) v[j] = bias[cb + j];
    } else {
        const u16* bias = (const u16*)biasv;
#pragma unroll
        for (int j = 0; j < 8; j++) v[j] = bf2f(bias[cb + j]);
    }
    v[0] += a0 * inv; v[1] += a1 * inv; v[2] += a2 * inv; v[3] += a3 * inv;
    v[4] += a4 * inv; v[5] += a5 * inv; v[6] += a6 * inv; v[7] += a7 * inv;

    float part = 0.f;
    if (cc0 < 16) {
#pragma unroll
        for (int j = 0; j < 8; j++) part += 0.5f * v[j] * v[j];
        long long o = (long long)node * 64 + head * 16 + cc0;
#pragma unroll
        for (int j = 0; j < 8; j++) stout(outv, o + j, v[j], f32);
        long long om = (long long)MEAN_OFF + o;
#pragma unroll
        for (int j = 0; j < 8; j++) stout(outv, om + j, v[j], f32);
    } else {
        long long os = (long long)STD_OFF + (long long)node * 64 + head * 16 + (cc0 - 16);
#pragma unroll
        for (int j = 0; j < 8; j++) {
            float s = softplusf(v[j] - 5.f) + 1e-10f;
            part += -logf(s) + 0.5f * s * s - 0.5f;
            stout(outv, os + j, s, f32);
        }
    }
    part += __shfl_xor(part, 1); part += __shfl_xor(part, 2);
    part += __shfl_xor(part, 4); part += __shfl_xor(part, 8);
    if (l == 0) stout(outv, (long long)IXZ_OFF + node, part * 0.25f, f32);
    if (t == 0) stout(outv, (long long)SKL_OFF, 0.f, f32);
}

// ---------------------------------------------------------------------------
extern "C" void kernel_launch(void* const* d_in, const int* in_sizes, int n_in,
                              void* d_out, int out_size, void* d_ws, size_t ws_size,
                              hipStream_t stream)
{
    const void* x    = d_in[0];
    const int*  ei   = (const int*)d_in[1];
    const void* w    = d_in[2];
    const void* att  = d_in[3];
    const void* bias = d_in[4];
    int E = in_sizes[1] / 2;

    // workspace (~11.3 MB): hb(fp8) | ai | aj | perm_src | counts | cursor |
    //                       done | lexcl | blocksum | sboff_g | wtg
    u8*    hb       = (u8*)d_ws;                       // NN*128 fp8
    float* ai       = (float*)(hb + (size_t)NN * 128);
    float* aj       = ai + NN * 4;
    int*   perm_src = (int*)(aj + NN * 4);             // E
    int*   counts   = perm_src + E;                    // NN
    int*   cursor   = counts + NN;                     // NN
    int*   done     = cursor + NN;                     // 1 (zeroed with counts/cursor)
    int*   lexcl    = done + 1;                        // NN
    int*   blocksum = lexcl + NN;                      // NB
    int*   sboff_g  = blocksum + NB;                   // 256
    u16*   wtg      = (u16*)(((uintptr_t)(sboff_g + 256) + 15) & ~(uintptr_t)15);

    k_wt<<<64, 256, 0, stream>>>(x, w, wtg, counts);
    k_gemm<<<NTILES, 256, 0, stream>>>(x, wtg, att, hb, ai, aj,
                                       ei + E, counts, E);
    k_scan1<<<NB, 256, 0, stream>>>(counts, lexcl, blocksum, done, sboff_g);
    k_fill<<<(E + 255) / 256, 256, 0, stream>>>(ei, lexcl, sboff_g,
                                                cursor, perm_src, E);
    k_agg<<<(NN * 16) / 256, 256, 0, stream>>>(lexcl, sboff_g, counts,
                                               perm_src, ai, aj, hb,
                                               bias, x, d_out);
}